// Round 1
// baseline (1003.435 us; speedup 1.0000x reference)
//
#include <hip/hip_runtime.h>
#include <hip/hip_bf16.h>
#include <stdint.h>

#define TOKENS 512
#define HDIM   2048
#define IDIM   1408
#define SIDIM  5632
#define NEXP   60
#define TOPK   4
#define NSLOTS (TOKENS*TOPK)   /* 2048 */
#define ROWPAD 64              /* padding rows so tail tiles read valid memory */

typedef __attribute__((ext_vector_type(8))) short bf16x8;
typedef __attribute__((ext_vector_type(4))) float f32x4;

__device__ __forceinline__ short f2bf(float f){
  uint32_t u = __float_as_uint(f);
  u = (u + 0x7fffu + ((u >> 16) & 1u)) >> 16;   // RNE
  return (short)(u & 0xffffu);
}

__device__ __forceinline__ bf16x8 pack8(float4 a, float4 b){
  bf16x8 r;
  r[0]=f2bf(a.x); r[1]=f2bf(a.y); r[2]=f2bf(a.z); r[3]=f2bf(a.w);
  r[4]=f2bf(b.x); r[5]=f2bf(b.y); r[6]=f2bf(b.z); r[7]=f2bf(b.w);
  return r;
}

__device__ __forceinline__ f32x4 zero4(){
  f32x4 z; z[0]=0.f; z[1]=0.f; z[2]=0.f; z[3]=0.f; return z;
}

__device__ __forceinline__ f32x4 mfma16(bf16x8 a, bf16x8 b, f32x4 c){
  return __builtin_amdgcn_mfma_f32_16x16x32_bf16(a, b, c, 0, 0, 0);
}

// ---------------- router: logits -> softmax -> top-4 + shared sigmoid gate ---
__global__ __launch_bounds__(64) void router_kernel(
    const float* __restrict__ x, const float* __restrict__ rw,
    const float* __restrict__ egw, int* __restrict__ topk_idx,
    float* __restrict__ topk_w, float* __restrict__ gates,
    int* __restrict__ counts)
{
  int t = blockIdx.x;
  int lane = threadIdx.x;
  const float* xr = x + (size_t)t*HDIM;
  float xv[HDIM/64];
  #pragma unroll
  for (int i=0;i<HDIM/64;i++) xv[i] = xr[lane + 64*i];

  float mylogit = -1e30f;
  for (int e=0;e<NEXP;e++){
    const float* w = rw + (size_t)e*HDIM;
    float acc = 0.f;
    #pragma unroll
    for (int i=0;i<HDIM/64;i++) acc += xv[i]*w[lane+64*i];
    #pragma unroll
    for (int s=32;s>0;s>>=1) acc += __shfl_xor(acc, s);
    if (lane == e) mylogit = acc;
  }
  { // shared-expert sigmoid gate
    float acc = 0.f;
    #pragma unroll
    for (int i=0;i<HDIM/64;i++) acc += xv[i]*egw[lane+64*i];
    #pragma unroll
    for (int s=32;s>0;s>>=1) acc += __shfl_xor(acc, s);
    if (lane == 0) gates[t] = 1.f/(1.f + __expf(-acc));
  }
  float m = mylogit;
  #pragma unroll
  for (int s=32;s>0;s>>=1) m = fmaxf(m, __shfl_xor(m, s));
  float p = (lane < NEXP) ? __expf(mylogit - m) : 0.f;
  float sum = p;
  #pragma unroll
  for (int s=32;s>0;s>>=1) sum += __shfl_xor(sum, s);
  float prob = p / sum;
  for (int k=0;k<TOPK;k++){
    float v = prob; int idx = lane;
    #pragma unroll
    for (int s=32;s>0;s>>=1){
      float ov = __shfl_xor(v, s); int oi = __shfl_xor(idx, s);
      if (ov > v || (ov == v && oi < idx)){ v = ov; idx = oi; }
    }
    if (lane == 0){
      topk_idx[t*TOPK+k] = idx;
      topk_w[t*TOPK+k]  = v;
      atomicAdd(&counts[idx], 1);
    }
    if (lane == idx) prob = -1e30f;
  }
}

// ---------------- exclusive prefix over 60 counts -----------------------------
__global__ void prefix_kernel(const int* __restrict__ counts, int* __restrict__ offsets)
{
  if (threadIdx.x == 0){
    int acc = 0;
    for (int e=0;e<NEXP;e++){ offsets[e] = acc; acc += counts[e]; }
    offsets[NEXP] = acc;
  }
}

// ---------------- assign slots, gather tokens (bf16), and make xb ------------
__global__ __launch_bounds__(256) void scatter_kernel(
    const float* __restrict__ x, const int* __restrict__ topk_idx,
    const int* __restrict__ offsets, int* __restrict__ fill,
    int* __restrict__ slot_of, __hip_bfloat16* __restrict__ xg,
    __hip_bfloat16* __restrict__ xb)
{
  int t = blockIdx.x, tid = threadIdx.x;
  __shared__ int sl[TOPK];
  if (tid == 0){
    for (int k=0;k<TOPK;k++){
      int e = topk_idx[t*TOPK+k];
      int pos = atomicAdd(&fill[e], 1);
      int s = offsets[e] + pos;
      slot_of[t*TOPK+k] = s;
      sl[k] = s;
    }
  }
  __syncthreads();
  const float4* xr = (const float4*)(x + (size_t)t*HDIM);
  float4 v0 = xr[tid*2], v1 = xr[tid*2+1];
  bf16x8 b = pack8(v0, v1);
  *(bf16x8*)((short*)xb + (size_t)t*HDIM + tid*8) = b;
  #pragma unroll
  for (int k=0;k<TOPK;k++)
    *(bf16x8*)((short*)xg + (size_t)sl[k]*HDIM + tid*8) = b;
}

// ---------------- fused gate+up GEMM with silu(g)*u epilogue ------------------
// offsets!=null: expert mode (e = blockIdx.y, rows = packed slots)
// offsets==null: shared mode  (m-tile = blockIdx.y)
__global__ __launch_bounds__(256) void gateup_kernel(
    const float* __restrict__ Wg_base, const float* __restrict__ Wu_base,
    const __hip_bfloat16* __restrict__ A, __hip_bfloat16* __restrict__ out,
    const int* __restrict__ offsets, int K, int NI)
{
  int m_start, m_end;
  const float *Wg = Wg_base, *Wu = Wu_base;
  if (offsets){
    int e = blockIdx.y;
    m_start = offsets[e]; m_end = offsets[e+1];
    size_t wo = (size_t)e * NI * K;
    Wg += wo; Wu += wo;
  } else {
    m_start = blockIdx.y * 64; m_end = m_start + 64;
  }
  if (m_start >= m_end) return;
  int lane = threadIdx.x & 63;
  int wave = threadIdx.x >> 6;
  int c16 = lane & 15, kq = lane >> 4;
  int wrow = blockIdx.x*64 + wave*16 + c16;         // weight row = output col
  const float* wg = Wg + (size_t)wrow*K + kq*8;
  const float* wu = Wu + (size_t)wrow*K + kq*8;
  const short* As = (const short*)A;

  for (int m0 = m_start; m0 < m_end; m0 += 64){
    int mrem = m_end - m0;
    const short* a0 = As + (size_t)(m0 + c16)*K + kq*8;
    f32x4 accg[4], accu[4];
    #pragma unroll
    for (int i=0;i<4;i++){ accg[i] = zero4(); accu[i] = zero4(); }
    for (int k0 = 0; k0 < K; k0 += 64){
      bf16x8 av[8];
      #pragma unroll
      for (int mf=0; mf<4; mf++){
        av[mf]   = *(const bf16x8*)(a0 + (size_t)mf*16*K + k0);
        av[4+mf] = *(const bf16x8*)(a0 + (size_t)mf*16*K + k0 + 32);
      }
      float4 g0 = *(const float4*)(wg + k0);
      float4 g1 = *(const float4*)(wg + k0 + 4);
      float4 g2 = *(const float4*)(wg + k0 + 32);
      float4 g3 = *(const float4*)(wg + k0 + 36);
      float4 u0 = *(const float4*)(wu + k0);
      float4 u1 = *(const float4*)(wu + k0 + 4);
      float4 u2 = *(const float4*)(wu + k0 + 32);
      float4 u3 = *(const float4*)(wu + k0 + 36);
      bf16x8 bg0 = pack8(g0,g1), bg1 = pack8(g2,g3);
      bf16x8 bu0 = pack8(u0,u1), bu1 = pack8(u2,u3);
      #pragma unroll
      for (int mf=0; mf<4; mf++){
        accg[mf] = mfma16(av[mf],   bg0, accg[mf]);
        accu[mf] = mfma16(av[mf],   bu0, accu[mf]);
        accg[mf] = mfma16(av[4+mf], bg1, accg[mf]);
        accu[mf] = mfma16(av[4+mf], bu1, accu[mf]);
      }
    }
    #pragma unroll
    for (int mf=0; mf<4; mf++){
      #pragma unroll
      for (int j=0;j<4;j++){
        int mrow = mf*16 + kq*4 + j;               // D row=(lane>>4)*4+j (+16*mf)
        if (mrow < mrem){
          float g = accg[mf][j], u = accu[mf][j];
          float s = g * u / (1.f + __expf(-g));    // silu(g)*u
          ((short*)out)[(size_t)(m0+mrow)*NI + wrow] = f2bf(s);
        }
      }
    }
  }
}

// ---------------- down-projection GEMM (fp32 out) -----------------------------
__global__ __launch_bounds__(256) void down_kernel(
    const float* __restrict__ W_base, const __hip_bfloat16* __restrict__ A,
    float* __restrict__ out, const int* __restrict__ offsets, int K, int NH)
{
  int m_start, m_end;
  const float* W = W_base;
  if (offsets){
    int e = blockIdx.y;
    m_start = offsets[e]; m_end = offsets[e+1];
    W += (size_t)e * NH * K;
  } else {
    m_start = blockIdx.y * 64; m_end = m_start + 64;
  }
  if (m_start >= m_end) return;
  int lane = threadIdx.x & 63;
  int wave = threadIdx.x >> 6;
  int c16 = lane & 15, kq = lane >> 4;
  int wrow = blockIdx.x*64 + wave*16 + c16;
  const float* wp = W + (size_t)wrow*K + kq*8;
  const short* As = (const short*)A;

  for (int m0 = m_start; m0 < m_end; m0 += 64){
    int mrem = m_end - m0;
    const short* a0 = As + (size_t)(m0 + c16)*K + kq*8;
    f32x4 acc[4];
    #pragma unroll
    for (int i=0;i<4;i++) acc[i] = zero4();
    for (int k0 = 0; k0 < K; k0 += 64){
      bf16x8 av[8];
      #pragma unroll
      for (int mf=0; mf<4; mf++){
        av[mf]   = *(const bf16x8*)(a0 + (size_t)mf*16*K + k0);
        av[4+mf] = *(const bf16x8*)(a0 + (size_t)mf*16*K + k0 + 32);
      }
      float4 w0 = *(const float4*)(wp + k0);
      float4 w1 = *(const float4*)(wp + k0 + 4);
      float4 w2 = *(const float4*)(wp + k0 + 32);
      float4 w3 = *(const float4*)(wp + k0 + 36);
      bf16x8 b0 = pack8(w0,w1), b1 = pack8(w2,w3);
      #pragma unroll
      for (int mf=0; mf<4; mf++){
        acc[mf] = mfma16(av[mf],   b0, acc[mf]);
        acc[mf] = mfma16(av[4+mf], b1, acc[mf]);
      }
    }
    #pragma unroll
    for (int mf=0; mf<4; mf++){
      #pragma unroll
      for (int j=0;j<4;j++){
        int mrow = mf*16 + kq*4 + j;
        if (mrow < mrem)
          out[(size_t)(m0+mrow)*NH + wrow] = acc[mf][j];
      }
    }
  }
}

// ---------------- final combine: sum top-4 weighted + gated shared -----------
__global__ __launch_bounds__(256) void combine_kernel(
    const float* __restrict__ dslot, const float* __restrict__ shdown,
    const int* __restrict__ slot_of, const float* __restrict__ topw,
    const float* __restrict__ gates, float* __restrict__ out)
{
  int t = blockIdx.x, tid = threadIdx.x;
  int4  sl = ((const int4*)slot_of)[t];
  float4 w = ((const float4*)topw)[t];
  float sg = gates[t];
  const float* r0 = dslot + (size_t)sl.x*HDIM;
  const float* r1 = dslot + (size_t)sl.y*HDIM;
  const float* r2 = dslot + (size_t)sl.z*HDIM;
  const float* r3 = dslot + (size_t)sl.w*HDIM;
  const float* rs = shdown + (size_t)t*HDIM;
  float* o = out + (size_t)t*HDIM;
  #pragma unroll
  for (int it=0; it<HDIM/(256*4); ++it){
    int h = (tid + it*256) * 4;
    float4 a0 = *(const float4*)(r0+h);
    float4 a1 = *(const float4*)(r1+h);
    float4 a2 = *(const float4*)(r2+h);
    float4 a3 = *(const float4*)(r3+h);
    float4 as = *(const float4*)(rs+h);
    float4 r;
    r.x = w.x*a0.x + w.y*a1.x + w.z*a2.x + w.w*a3.x + sg*as.x;
    r.y = w.x*a0.y + w.y*a1.y + w.z*a2.y + w.w*a3.y + sg*as.y;
    r.z = w.x*a0.z + w.y*a1.z + w.z*a2.z + w.w*a3.z + sg*as.z;
    r.w = w.x*a0.w + w.y*a1.w + w.z*a2.w + w.w*a3.w + sg*as.w;
    *(float4*)(o+h) = r;
  }
}

extern "C" void kernel_launch(void* const* d_in, const int* in_sizes, int n_in,
                              void* d_out, int out_size, void* d_ws, size_t ws_size,
                              hipStream_t stream)
{
  const float* x         = (const float*)d_in[0];
  const float* router_w  = (const float*)d_in[1];
  const float* gate_w    = (const float*)d_in[2];
  const float* up_w      = (const float*)d_in[3];
  const float* down_w    = (const float*)d_in[4];
  const float* sh_gate_w = (const float*)d_in[5];
  const float* sh_up_w   = (const float*)d_in[6];
  const float* sh_down_w = (const float*)d_in[7];
  const float* eg_w      = (const float*)d_in[8];

  char* p = (char*)d_ws;
  auto alloc = [&](size_t bytes)->char*{
    char* r = p; p += (bytes + 255) & ~(size_t)255; return r;
  };
  int*   counts   = (int*)  alloc(NEXP*4);
  int*   fill     = (int*)  alloc(NEXP*4);
  int*   offsets  = (int*)  alloc((NEXP+1)*4);
  int*   topk_idx = (int*)  alloc(NSLOTS*4);
  float* topk_w   = (float*)alloc(NSLOTS*4);
  int*   slot_of  = (int*)  alloc(NSLOTS*4);
  float* gates    = (float*)alloc(TOKENS*4);
  __hip_bfloat16* xb    = (__hip_bfloat16*)alloc((size_t)TOKENS*HDIM*2);
  __hip_bfloat16* xg    = (__hip_bfloat16*)alloc((size_t)(NSLOTS+ROWPAD)*HDIM*2);
  __hip_bfloat16* act   = (__hip_bfloat16*)alloc((size_t)(NSLOTS+ROWPAD)*IDIM*2);
  __hip_bfloat16* shact = (__hip_bfloat16*)alloc((size_t)TOKENS*SIDIM*2);
  float* dslot  = (float*)alloc((size_t)NSLOTS*HDIM*4);
  float* shdown = (float*)alloc((size_t)TOKENS*HDIM*4);
  if ((size_t)(p - (char*)d_ws) > ws_size) return;  // ws too small: fail loudly

  hipMemsetAsync(counts, 0, NEXP*4, stream);
  hipMemsetAsync(fill,   0, NEXP*4, stream);

  router_kernel <<<TOKENS, 64, 0, stream>>>(x, router_w, eg_w, topk_idx, topk_w, gates, counts);
  prefix_kernel <<<1, 64, 0, stream>>>(counts, offsets);
  scatter_kernel<<<TOKENS, 256, 0, stream>>>(x, topk_idx, offsets, fill, slot_of, xg, xb);

  gateup_kernel<<<dim3(IDIM/64,  NEXP),      256, 0, stream>>>(gate_w,    up_w,    xg,    act,   offsets, HDIM,  IDIM);
  down_kernel  <<<dim3(HDIM/64,  NEXP),      256, 0, stream>>>(down_w,    act,     dslot, offsets, IDIM,  HDIM);
  gateup_kernel<<<dim3(SIDIM/64, TOKENS/64), 256, 0, stream>>>(sh_gate_w, sh_up_w, xb,    shact, nullptr, HDIM,  SIDIM);
  down_kernel  <<<dim3(HDIM/64,  TOKENS/64), 256, 0, stream>>>(sh_down_w, shact,   shdown, nullptr, SIDIM, HDIM);

  combine_kernel<<<TOKENS, 256, 0, stream>>>(dslot, shdown, slot_of, topk_w, gates, (float*)d_out);
}